// Round 1
// 98.847 us; speedup vs baseline: 1.1255x; 1.1255x over previous
//
#include <hip/hip_runtime.h>
#include <hip/hip_bf16.h>
#include <cstdint>
#include <cstddef>

#define N_ROWS 8192
#define DIM    512
#define NKT    8          // K-tiles of 64
#define C_EXPSCALE 14.4269504088896340736f   // 10*log2(e); exp(sim-10)=exp2((cos-1)*this)

typedef __attribute__((ext_vector_type(8))) short bf16x8;
typedef __attribute__((ext_vector_type(4))) float f32x4;

__device__ __forceinline__ ushort f2bf(float x) {
  union { float f; uint32_t u; } c; c.f = x;
  uint32_t r = (c.u + 0x7fffu + ((c.u >> 16) & 1u)) >> 16;
  return (ushort)r;
}

// ---------------- prep: fp32 row norms, fp32 diag, bf16 normalized copies ----
// 4 rows per 256-thread block (1 wave per row); also zeroes row/col sums
// (replaces the hipMemsetAsync dispatch).
__global__ __launch_bounds__(256) void prep_kernel(const float* __restrict__ V,
                                                   const float* __restrict__ U,
                                                   ushort* __restrict__ Vn,
                                                   ushort* __restrict__ Un,
                                                   float* __restrict__ diag,
                                                   float* __restrict__ row_sum,
                                                   float* __restrict__ col_sum) {
  const int row = blockIdx.x * 4 + (threadIdx.x >> 6);
  const int l = threadIdx.x & 63;
  const float4* v4 = (const float4*)(V + (size_t)row * DIM) + l * 2;
  const float4* u4 = (const float4*)(U + (size_t)row * DIM) + l * 2;
  float4 a0 = v4[0], a1 = v4[1];
  float4 b0 = u4[0], b1 = u4[1];
  float sv = a0.x*a0.x + a0.y*a0.y + a0.z*a0.z + a0.w*a0.w
           + a1.x*a1.x + a1.y*a1.y + a1.z*a1.z + a1.w*a1.w;
  float su = b0.x*b0.x + b0.y*b0.y + b0.z*b0.z + b0.w*b0.w
           + b1.x*b1.x + b1.y*b1.y + b1.z*b1.z + b1.w*b1.w;
  float sd = a0.x*b0.x + a0.y*b0.y + a0.z*b0.z + a0.w*b0.w
           + a1.x*b1.x + a1.y*b1.y + a1.z*b1.z + a1.w*b1.w;
#pragma unroll
  for (int m = 1; m < 64; m <<= 1) {
    sv += __shfl_xor(sv, m, 64);
    su += __shfl_xor(su, m, 64);
    sd += __shfl_xor(sd, m, 64);
  }
  const float rv = 1.0f / fmaxf(sqrtf(sv), 1e-8f);
  const float ru = 1.0f / fmaxf(sqrtf(su), 1e-8f);
  if (l == 0) {
    diag[row] = sd * rv * ru * 10.0f;
    row_sum[row] = 0.0f;
    col_sum[row] = 0.0f;
  }

  const float av[8] = {a0.x, a0.y, a0.z, a0.w, a1.x, a1.y, a1.z, a1.w};
  const float bv[8] = {b0.x, b0.y, b0.z, b0.w, b1.x, b1.y, b1.z, b1.w};
  union { ushort us[8]; uint4 q; } pv, pu;
#pragma unroll
  for (int j = 0; j < 8; ++j) {
    pv.us[j] = f2bf(av[j] * rv);
    pu.us[j] = f2bf(bv[j] * ru);
  }
  *(uint4*)(Vn + (size_t)row * DIM + l * 8) = pv.q;
  *(uint4*)(Un + (size_t)row * DIM + l * 8) = pu.q;
}

// ---- 256x256 GEMM (bf16 MFMA) + exp(sim-10) + row/col sums ----
// 8-phase schedule (T3+T4 template): per 2 K-tiles, 8 phases, each phase =
// {ds_read one quadrant || issue 1 half-tile global_load_lds -> barrier ->
//  lgkmcnt(0) -> setprio(1) 16 MFMA setprio(0) -> barrier}.
// Counted vmcnt(4) at P4/P8 only (never 0 mid-loop): 2 half-tiles stay in
// flight across barriers. Stage-half order derived from LDS liveness:
//   buf c: A-halves read in P1+P3, B-halves in P1+P2
//   P1:(2t+1).B1  P2:(2t+1).A1  P3:(2t+2).B0  P4:(2t+2).B1 +vmcnt(4)
//   P5:(2t+2).A0  P6:(2t+2).A1  P7:(2t+3).B0  P8:(2t+3).A0 +vmcnt(4)
#define AREG(s,h) ((s)*32768 + (h)*16384)
#define BREG(s,h) (65536 + (s)*32768 + (h)*16384)

__global__ __launch_bounds__(512, 2) void gemm_lse_kernel(const ushort* __restrict__ Vn,
                                                          const ushort* __restrict__ Un,
                                                          float* __restrict__ row_sum,
                                                          float* __restrict__ col_sum) {
  __shared__ ushort Tile[65536];   // 128 KiB

  const int tid  = threadIdx.x;
  const int lane = tid & 63;
  const int wid  = tid >> 6;
  const int wm   = wid >> 2;       // 0..1
  const int wn   = wid & 3;        // 0..3
  const int l15  = lane & 15;
  const int lhi  = lane >> 4;      // 0..3
  const int sw7  = l15 & 7;

  // XCD map: 8 XCDs tile the 32x32 grid as 4x2 supergrid of 8x16 each
  const int bid  = blockIdx.x;
  const int xcd  = bid & 7;
  const int x    = bid >> 3;
  const int rt   = (xcd >> 1) * 8 + (x >> 4);
  const int ct   = (xcd & 1) * 16 + (x & 15);
  const int br   = rt << 8;
  const int bc   = ct << 8;

  auto stage = [&](const ushort* __restrict__ src, int growbase, int kt, int region) {
#pragma unroll
    for (int i = 0; i < 2; ++i) {
      const int idx = i * 512 + tid;
      const int r   = idx >> 3;
      const int seg = (idx & 7) ^ (r & 7);           // inverse-swizzled source
      const ushort* g = src + (size_t)(growbase + r) * DIM + kt * 64 + seg * 8;
      __builtin_amdgcn_global_load_lds(
          (const __attribute__((address_space(1))) unsigned int*)g,
          (__attribute__((address_space(3))) unsigned int*)((char*)Tile + region + i * 8192 + wid * 1024),
          16, 0, 0);
    }
  };
  auto stgA = [&](int buf, int half, int kt) { stage(Vn, br + half * 128, kt, AREG(buf, half)); };
  auto stgB = [&](int buf, int half, int kt) { stage(Un, bc + half * 128, kt, BREG(buf, half)); };

  auto rdA = [&](int s, int m, int kk) -> bf16x8 {
    const int r    = m * 16 + l15;
    const int slot = ((kk << 2) | lhi) ^ sw7;        // swizzled read
    return *(const bf16x8*)((const char*)Tile + (s * 32768 + wm * 16384 + r * 128 + slot * 16));
  };
  auto rdB = [&](int s, int n, int kk) -> bf16x8 {
    const int r    = (wn & 1) * 64 + n * 16 + l15;
    const int slot = ((kk << 2) | lhi) ^ sw7;
    return *(const bf16x8*)((const char*)Tile + (65536 + s * 32768 + (wn >> 1) * 16384 + r * 128 + slot * 16));
  };

  f32x4 acc[8][4];
#pragma unroll
  for (int m = 0; m < 8; ++m)
#pragma unroll
    for (int n = 0; n < 4; ++n) acc[m][n] = (f32x4){0.f, 0.f, 0.f, 0.f};

  bf16x8 A0[4][2], A1[4][2], Bf[4][2];

  auto ldA = [&](bf16x8 (&A)[4][2], int s, int mb) {
#pragma unroll
    for (int m = 0; m < 4; ++m) { A[m][0] = rdA(s, mb + m, 0); A[m][1] = rdA(s, mb + m, 1); }
  };
  auto ldB = [&](int s, int nb) {
#pragma unroll
    for (int n = 0; n < 2; ++n) { Bf[nb + n][0] = rdB(s, nb + n, 0); Bf[nb + n][1] = rdB(s, nb + n, 1); }
  };
  auto quad = [&](int mb, int nb, bf16x8 (&A)[4][2]) {
    __builtin_amdgcn_s_setprio(1);
#pragma unroll
    for (int m = 0; m < 4; ++m)
#pragma unroll
      for (int n = 0; n < 2; ++n) {
        acc[mb + m][nb + n] = __builtin_amdgcn_mfma_f32_16x16x32_bf16(A[m][0], Bf[nb + n][0], acc[mb + m][nb + n], 0, 0, 0);
        acc[mb + m][nb + n] = __builtin_amdgcn_mfma_f32_16x16x32_bf16(A[m][1], Bf[nb + n][1], acc[mb + m][nb + n], 0, 0, 0);
      }
    __builtin_amdgcn_s_setprio(0);
  };

  // prologue: tile0 complete + tile1 {B0,A0} in flight (steady-state invariant)
  stgA(0, 0, 0); stgA(0, 1, 0); stgB(0, 0, 0); stgB(0, 1, 0);
  stgB(1, 0, 1); stgA(1, 0, 1);
  asm volatile("s_waitcnt vmcnt(4)" ::: "memory");
  __builtin_amdgcn_s_barrier();

#pragma unroll
  for (int t = 0; t < NKT / 2; ++t) {
    const bool s1 = (t < NKT / 2 - 1);
    const int k1 = 2 * t + 1, k2 = 2 * t + 2, k3 = 2 * t + 3;

    // P1: buf0 quad (m0-3 x n0-1)         stage (2t+1).B1
    ldA(A0, 0, 0); ldB(0, 0);
    stgB(1, 1, k1);
    asm volatile("s_waitcnt lgkmcnt(8)" ::: "memory");
    __builtin_amdgcn_s_barrier();
    asm volatile("s_waitcnt lgkmcnt(0)" ::: "memory");
    __builtin_amdgcn_sched_barrier(0);
    quad(0, 0, A0);
    __builtin_amdgcn_s_barrier();

    // P2: buf0 quad (m0-3 x n2-3)         stage (2t+1).A1
    ldB(0, 2);
    stgA(1, 1, k1);
    __builtin_amdgcn_s_barrier();
    asm volatile("s_waitcnt lgkmcnt(0)" ::: "memory");
    __builtin_amdgcn_sched_barrier(0);
    quad(0, 2, A0);
    __builtin_amdgcn_s_barrier();

    // P3: buf0 quad (m4-7 x n0-1)         stage (2t+2).B0  (buf0.B dead after P2)
    ldA(A1, 0, 4);
    if (s1) stgB(0, 0, k2);
    __builtin_amdgcn_s_barrier();
    asm volatile("s_waitcnt lgkmcnt(0)" ::: "memory");
    __builtin_amdgcn_sched_barrier(0);
    quad(4, 0, A1);
    __builtin_amdgcn_s_barrier();

    // P4: buf0 quad (m4-7 x n2-3)         stage (2t+2).B1; drain tile 2t+1
    if (s1) {
      stgB(0, 1, k2);
      asm volatile("s_waitcnt vmcnt(4)" ::: "memory");
    } else {
      asm volatile("s_waitcnt vmcnt(0)" ::: "memory");
    }
    __builtin_amdgcn_s_barrier();
    quad(4, 2, A1);
    __builtin_amdgcn_s_barrier();

    // P5: buf1 quad (m0-3 x n0-1)         stage (2t+2).A0  (buf0.A dead after P3)
    ldA(A0, 1, 0); ldB(1, 0);
    if (s1) stgA(0, 0, k2);
    asm volatile("s_waitcnt lgkmcnt(8)" ::: "memory");
    __builtin_amdgcn_s_barrier();
    asm volatile("s_waitcnt lgkmcnt(0)" ::: "memory");
    __builtin_amdgcn_sched_barrier(0);
    quad(0, 0, A0);
    __builtin_amdgcn_s_barrier();

    // P6: buf1 quad (m0-3 x n2-3)         stage (2t+2).A1
    ldB(1, 2);
    if (s1) stgA(0, 1, k2);
    __builtin_amdgcn_s_barrier();
    asm volatile("s_waitcnt lgkmcnt(0)" ::: "memory");
    __builtin_amdgcn_sched_barrier(0);
    quad(0, 2, A0);
    __builtin_amdgcn_s_barrier();

    // P7: buf1 quad (m4-7 x n0-1)         stage (2t+3).B0  (buf1.B dead after P6)
    ldA(A1, 1, 4);
    if (s1) stgB(1, 0, k3);
    __builtin_amdgcn_s_barrier();
    asm volatile("s_waitcnt lgkmcnt(0)" ::: "memory");
    __builtin_amdgcn_sched_barrier(0);
    quad(4, 0, A1);
    __builtin_amdgcn_s_barrier();

    // P8: buf1 quad (m4-7 x n2-3)         stage (2t+3).A0; drain tile 2t+2
    if (s1) {
      stgA(1, 0, k3);
      asm volatile("s_waitcnt vmcnt(4)" ::: "memory");
    }
    __builtin_amdgcn_s_barrier();
    quad(4, 2, A1);
    __builtin_amdgcn_s_barrier();
  }

  // ---- epilogue: exp(sim-10), row/col partial sums (reuse tile LDS) ----
  float* red_row = (float*)Tile;           // [4][256] floats (by wn)
  float* red_col = (float*)Tile + 1024;    // [2][256] floats (by wm)

#pragma unroll
  for (int m = 0; m < 8; ++m)
#pragma unroll
    for (int n = 0; n < 4; ++n) {
      f32x4 v = acc[m][n];
#pragma unroll
      for (int r = 0; r < 4; ++r) v[r] = __builtin_amdgcn_exp2f((v[r] - 1.0f) * C_EXPSCALE);
      acc[m][n] = v;
    }

#pragma unroll
  for (int m = 0; m < 8; ++m)
#pragma unroll
    for (int r = 0; r < 4; ++r) {
      float s = acc[m][0][r] + acc[m][1][r] + acc[m][2][r] + acc[m][3][r];
      s += __shfl_xor(s, 1, 64);
      s += __shfl_xor(s, 2, 64);
      s += __shfl_xor(s, 4, 64);
      s += __shfl_xor(s, 8, 64);
      if (l15 == 0) red_row[wn * 256 + wm * 128 + m * 16 + lhi * 4 + r] = s;
    }
#pragma unroll
  for (int n = 0; n < 4; ++n) {
    float s = 0.f;
#pragma unroll
    for (int m = 0; m < 8; ++m)
      s += acc[m][n][0] + acc[m][n][1] + acc[m][n][2] + acc[m][n][3];
    s += __shfl_xor(s, 16, 64);
    s += __shfl_xor(s, 32, 64);
    if (lane < 16) red_col[wm * 256 + wn * 64 + n * 16 + lane] = s;
  }
  __syncthreads();

  if (tid < 256) {
    float s = red_row[tid] + red_row[256 + tid] + red_row[512 + tid] + red_row[768 + tid];
    atomicAdd(&row_sum[br + tid], s);
  } else {
    const int c = tid - 256;
    float s = red_col[c] + red_col[256 + c];
    atomicAdd(&col_sum[bc + c], s);
  }
}

// ---------------- finalize ----------------
__global__ __launch_bounds__(1024) void finalize_kernel(const float* __restrict__ row_sum,
                                                        const float* __restrict__ col_sum,
                                                        const float* __restrict__ diag,
                                                        float* __restrict__ out) {
  __shared__ float sred[1024];
  float acc = 0.0f;
  for (int i = threadIdx.x; i < N_ROWS; i += 1024) {
    const float lse_r = 10.0f + logf(row_sum[i]);
    const float lse_c = 10.0f + logf(col_sum[i]);
    acc += 0.75f * lse_r + 0.25f * lse_c - diag[i];
  }
  sred[threadIdx.x] = acc;
  __syncthreads();
  for (int s = 512; s > 0; s >>= 1) {
    if ((int)threadIdx.x < s) sred[threadIdx.x] += sred[threadIdx.x + s];
    __syncthreads();
  }
  if (threadIdx.x == 0) out[0] = sred[0] / (float)N_ROWS;
}

extern "C" void kernel_launch(void* const* d_in, const int* in_sizes, int n_in,
                              void* d_out, int out_size, void* d_ws, size_t ws_size,
                              hipStream_t stream) {
  const float* V = (const float*)d_in[0];
  const float* U = (const float*)d_in[1];
  float* out = (float*)d_out;

  char* ws = (char*)d_ws;
  ushort* Vn      = (ushort*)(ws);
  ushort* Un      = (ushort*)(ws + 8388608);
  float*  diag    = (float*)(ws + 16777216);
  float*  row_sum = (float*)(ws + 16777216 + 32768);
  float*  col_sum = (float*)(ws + 16777216 + 65536);

  prep_kernel<<<N_ROWS / 4, 256, 0, stream>>>(V, U, Vn, Un, diag, row_sum, col_sum);
  gemm_lse_kernel<<<(N_ROWS / 256) * (N_ROWS / 256), 512, 0, stream>>>(Vn, Un, row_sum, col_sum);
  finalize_kernel<<<1, 1024, 0, stream>>>(row_sum, col_sum, diag, out);
}

// Round 2
// 98.813 us; speedup vs baseline: 1.1259x; 1.0003x over previous
//
#include <hip/hip_runtime.h>
#include <hip/hip_bf16.h>
#include <cstdint>
#include <cstddef>

#define N_ROWS 8192
#define DIM    512
#define NKT    8          // K-tiles of 64
#define C_EXPSCALE 14.4269504088896340736f   // 10*log2(e); exp(sim-10)=exp2((cos-1)*this)

typedef __attribute__((ext_vector_type(8))) short bf16x8;
typedef __attribute__((ext_vector_type(4))) float f32x4;

__device__ __forceinline__ ushort f2bf(float x) {
  union { float f; uint32_t u; } c; c.f = x;
  uint32_t r = (c.u + 0x7fffu + ((c.u >> 16) & 1u)) >> 16;
  return (ushort)r;
}

// ---------------- prep: fp32 row norms, fp32 diag, bf16 normalized copies ----
__global__ __launch_bounds__(256) void prep_kernel(const float* __restrict__ V,
                                                   const float* __restrict__ U,
                                                   ushort* __restrict__ Vn,
                                                   ushort* __restrict__ Un,
                                                   float* __restrict__ diag,
                                                   float* __restrict__ row_sum,
                                                   float* __restrict__ col_sum) {
  const int row = blockIdx.x * 4 + (threadIdx.x >> 6);
  const int l = threadIdx.x & 63;
  const float4* v4 = (const float4*)(V + (size_t)row * DIM) + l * 2;
  const float4* u4 = (const float4*)(U + (size_t)row * DIM) + l * 2;
  float4 a0 = v4[0], a1 = v4[1];
  float4 b0 = u4[0], b1 = u4[1];
  float sv = a0.x*a0.x + a0.y*a0.y + a0.z*a0.z + a0.w*a0.w
           + a1.x*a1.x + a1.y*a1.y + a1.z*a1.z + a1.w*a1.w;
  float su = b0.x*b0.x + b0.y*b0.y + b0.z*b0.z + b0.w*b0.w
           + b1.x*b1.x + b1.y*b1.y + b1.z*b1.z + b1.w*b1.w;
  float sd = a0.x*b0.x + a0.y*b0.y + a0.z*b0.z + a0.w*b0.w
           + a1.x*b1.x + a1.y*b1.y + a1.z*b1.z + a1.w*b1.w;
#pragma unroll
  for (int m = 1; m < 64; m <<= 1) {
    sv += __shfl_xor(sv, m, 64);
    su += __shfl_xor(su, m, 64);
    sd += __shfl_xor(sd, m, 64);
  }
  const float rv = 1.0f / fmaxf(sqrtf(sv), 1e-8f);
  const float ru = 1.0f / fmaxf(sqrtf(su), 1e-8f);
  if (l == 0) {
    diag[row] = sd * rv * ru * 10.0f;
    row_sum[row] = 0.0f;
    col_sum[row] = 0.0f;
  }

  const float av[8] = {a0.x, a0.y, a0.z, a0.w, a1.x, a1.y, a1.z, a1.w};
  const float bv[8] = {b0.x, b0.y, b0.z, b0.w, b1.x, b1.y, b1.z, b1.w};
  union { ushort us[8]; uint4 q; } pv, pu;
#pragma unroll
  for (int j = 0; j < 8; ++j) {
    pv.us[j] = f2bf(av[j] * rv);
    pu.us[j] = f2bf(bv[j] * ru);
  }
  *(uint4*)(Vn + (size_t)row * DIM + l * 8) = pv.q;
  *(uint4*)(Un + (size_t)row * DIM + l * 8) = pu.q;
}

// ---- 256x256 GEMM (bf16 MFMA) + exp(sim-10) + row/col sums ----
// 8-phase counted-vmcnt schedule; per-phase fragment plan = hold-B/stream-A:
//   P1: ldB(all 8) + ldA(m0-1), MFMA m0-1 x n0-3
//   P2: ldA(m2-3),              MFMA m2-3 x n0-3
//   P3: ldA(m4-5),              MFMA m4-5 x n0-3
//   P4: ldA(m6-7),              MFMA m6-7 x n0-3
// Peak fragment VGPRs 96 -> 48; freed regs hold hoisted LDS/global base
// addresses so per-phase address VALU ~0 (every ds_read is base+imm, every
// global_load_lds is base+kt*128 folded into the inst offset).
// Staging ledger (unchanged, verified): prologue tile0 x4 + tile1{B0,A0};
//   P1:+k1.B1 P2:+k1.A1 P3:+k2.B0 P4:+k2.B1,vmcnt(4) P5:+k2.A0 P6:+k2.A1
//   P7:+k3.B0 P8:+k3.A0,vmcnt(4); last group degrades to vmcnt(0) at P4.
#define AREG(s,h) ((s)*32768 + (h)*16384)
#define BREG(s,h) (65536 + (s)*32768 + (h)*16384)

__global__ __launch_bounds__(512, 2) void gemm_lse_kernel(const ushort* __restrict__ Vn,
                                                          const ushort* __restrict__ Un,
                                                          float* __restrict__ row_sum,
                                                          float* __restrict__ col_sum) {
  __shared__ ushort Tile[65536];   // 128 KiB

  const int tid  = threadIdx.x;
  const int lane = tid & 63;
  const int wid  = tid >> 6;
  const int wm   = wid >> 2;       // 0..1
  const int wn   = wid & 3;        // 0..3
  const int l15  = lane & 15;
  const int lhi  = lane >> 4;      // 0..3
  const int sw7  = l15 & 7;

  // XCD map: 8 XCDs tile the 32x32 grid as 4x2 supergrid of 8x16 each
  const int bid  = blockIdx.x;
  const int xcd  = bid & 7;
  const int x    = bid >> 3;
  const int rt   = (xcd >> 1) * 8 + (x >> 4);
  const int ct   = (xcd & 1) * 16 + (x & 15);
  const int br   = rt << 8;
  const int bc   = ct << 8;

  // ---- hoisted per-lane global staging bases (8 x 64-bit) ----
  const int r0 = tid >> 3,          seg0 = (tid & 7) ^ (r0 & 7);
  const int r1 = (512 + tid) >> 3,  seg1 = ((512 + tid) & 7) ^ (r1 & 7);
  const ushort* gA0_0 = Vn + (size_t)(br + r0) * DIM + seg0 * 8;
  const ushort* gA0_1 = Vn + (size_t)(br + r1) * DIM + seg1 * 8;
  const ushort* gA1_0 = Vn + (size_t)(br + 128 + r0) * DIM + seg0 * 8;
  const ushort* gA1_1 = Vn + (size_t)(br + 128 + r1) * DIM + seg1 * 8;
  const ushort* gB0_0 = Un + (size_t)(bc + r0) * DIM + seg0 * 8;
  const ushort* gB0_1 = Un + (size_t)(bc + r1) * DIM + seg1 * 8;
  const ushort* gB1_0 = Un + (size_t)(bc + 128 + r0) * DIM + seg0 * 8;
  const ushort* gB1_1 = Un + (size_t)(bc + 128 + r1) * DIM + seg1 * 8;

  auto stg = [&](const ushort* g0, const ushort* g1, int kt, int region) {
    __builtin_amdgcn_global_load_lds(
        (const __attribute__((address_space(1))) unsigned int*)(g0 + kt * 64),
        (__attribute__((address_space(3))) unsigned int*)((char*)Tile + region + wid * 1024),
        16, 0, 0);
    __builtin_amdgcn_global_load_lds(
        (const __attribute__((address_space(1))) unsigned int*)(g1 + kt * 64),
        (__attribute__((address_space(3))) unsigned int*)((char*)Tile + region + 8192 + wid * 1024),
        16, 0, 0);
  };
  auto stgA = [&](int buf, int half, int kt) {
    stg(half ? gA1_0 : gA0_0, half ? gA1_1 : gA0_1, kt, AREG(buf, half));
  };
  auto stgB = [&](int buf, int half, int kt) {
    stg(half ? gB1_0 : gB0_0, half ? gB1_1 : gB0_1, kt, BREG(buf, half));
  };

  // ---- hoisted LDS read bases (8 x 32-bit); slot(kk=1) = slot(kk=0)^4 ----
  const char* TB = (const char*)Tile;
  const int aoff = wm * 16384 + l15 * 128;
  const int boff = (wn >> 1) * 16384 + ((wn & 1) * 64 + l15) * 128;
  const int sl0  = ((0 | lhi) ^ sw7) * 16;
  const int sl1  = ((4 | lhi) ^ sw7) * 16;
  const char* pA[2][2] = { { TB + aoff + sl0,          TB + aoff + sl1 },
                           { TB + 32768 + aoff + sl0,  TB + 32768 + aoff + sl1 } };
  const char* pB[2][2] = { { TB + 65536 + boff + sl0,  TB + 65536 + boff + sl1 },
                           { TB + 98304 + boff + sl0,  TB + 98304 + boff + sl1 } };

  f32x4 acc[8][4];
#pragma unroll
  for (int m = 0; m < 8; ++m)
#pragma unroll
    for (int n = 0; n < 4; ++n) acc[m][n] = (f32x4){0.f, 0.f, 0.f, 0.f};

  bf16x8 Bf[4][2], AfA[2][2], AfB[2][2];

  auto ldB8 = [&](int s) {
#pragma unroll
    for (int n = 0; n < 4; ++n) {
      Bf[n][0] = *(const bf16x8*)(pB[s][0] + n * 2048);
      Bf[n][1] = *(const bf16x8*)(pB[s][1] + n * 2048);
    }
  };
  auto ldA2 = [&](bf16x8 (&A)[2][2], int s, int mb) {
#pragma unroll
    for (int m = 0; m < 2; ++m) {
      A[m][0] = *(const bf16x8*)(pA[s][0] + (mb + m) * 2048);
      A[m][1] = *(const bf16x8*)(pA[s][1] + (mb + m) * 2048);
    }
  };
  auto quad2 = [&](int mb, bf16x8 (&A)[2][2]) {
    __builtin_amdgcn_s_setprio(1);
#pragma unroll
    for (int m = 0; m < 2; ++m)
#pragma unroll
      for (int n = 0; n < 4; ++n) {
        acc[mb + m][n] = __builtin_amdgcn_mfma_f32_16x16x32_bf16(A[m][0], Bf[n][0], acc[mb + m][n], 0, 0, 0);
        acc[mb + m][n] = __builtin_amdgcn_mfma_f32_16x16x32_bf16(A[m][1], Bf[n][1], acc[mb + m][n], 0, 0, 0);
      }
    __builtin_amdgcn_s_setprio(0);
  };

  // prologue: tile0 complete + tile1 {B0,A0} in flight (steady-state invariant)
  stgA(0, 0, 0); stgA(0, 1, 0); stgB(0, 0, 0); stgB(0, 1, 0);
  stgB(1, 0, 1); stgA(1, 0, 1);
  asm volatile("s_waitcnt vmcnt(4)" ::: "memory");
  __builtin_amdgcn_s_barrier();

#pragma unroll
  for (int t = 0; t < NKT / 2; ++t) {
    const bool s1 = (t < NKT / 2 - 1);
    const int k1 = 2 * t + 1, k2 = 2 * t + 2, k3 = 2 * t + 3;

    // ---------------- tile 2t (buf 0) ----------------
    // P1
    ldB8(0); ldA2(AfA, 0, 0);
    stgB(1, 1, k1);
    asm volatile("s_waitcnt lgkmcnt(8)" ::: "memory");
    __builtin_amdgcn_s_barrier();
    asm volatile("s_waitcnt lgkmcnt(0)" ::: "memory");
    __builtin_amdgcn_sched_barrier(0);
    quad2(0, AfA);
    __builtin_amdgcn_s_barrier();

    // P2
    ldA2(AfB, 0, 2);
    stgA(1, 1, k1);
    __builtin_amdgcn_s_barrier();
    asm volatile("s_waitcnt lgkmcnt(0)" ::: "memory");
    __builtin_amdgcn_sched_barrier(0);
    quad2(2, AfB);
    __builtin_amdgcn_s_barrier();

    // P3
    ldA2(AfA, 0, 4);
    if (s1) stgB(0, 0, k2);
    __builtin_amdgcn_s_barrier();
    asm volatile("s_waitcnt lgkmcnt(0)" ::: "memory");
    __builtin_amdgcn_sched_barrier(0);
    quad2(4, AfA);
    __builtin_amdgcn_s_barrier();

    // P4 (+drain tile k1)
    ldA2(AfB, 0, 6);
    if (s1) {
      stgB(0, 1, k2);
      asm volatile("s_waitcnt vmcnt(4)" ::: "memory");
    } else {
      asm volatile("s_waitcnt vmcnt(0)" ::: "memory");
    }
    __builtin_amdgcn_s_barrier();
    asm volatile("s_waitcnt lgkmcnt(0)" ::: "memory");
    __builtin_amdgcn_sched_barrier(0);
    quad2(6, AfB);
    __builtin_amdgcn_s_barrier();

    // ---------------- tile 2t+1 (buf 1) ----------------
    // P5
    ldB8(1); ldA2(AfA, 1, 0);
    if (s1) stgA(0, 0, k2);
    asm volatile("s_waitcnt lgkmcnt(8)" ::: "memory");
    __builtin_amdgcn_s_barrier();
    asm volatile("s_waitcnt lgkmcnt(0)" ::: "memory");
    __builtin_amdgcn_sched_barrier(0);
    quad2(0, AfA);
    __builtin_amdgcn_s_barrier();

    // P6
    ldA2(AfB, 1, 2);
    if (s1) stgA(0, 1, k2);
    __builtin_amdgcn_s_barrier();
    asm volatile("s_waitcnt lgkmcnt(0)" ::: "memory");
    __builtin_amdgcn_sched_barrier(0);
    quad2(2, AfB);
    __builtin_amdgcn_s_barrier();

    // P7
    ldA2(AfA, 1, 4);
    if (s1) stgB(1, 0, k3);
    __builtin_amdgcn_s_barrier();
    asm volatile("s_waitcnt lgkmcnt(0)" ::: "memory");
    __builtin_amdgcn_sched_barrier(0);
    quad2(4, AfA);
    __builtin_amdgcn_s_barrier();

    // P8 (+drain tile k2)
    ldA2(AfB, 1, 6);
    if (s1) {
      stgA(1, 0, k3);
      asm volatile("s_waitcnt vmcnt(4)" ::: "memory");
    }
    __builtin_amdgcn_s_barrier();
    asm volatile("s_waitcnt lgkmcnt(0)" ::: "memory");
    __builtin_amdgcn_sched_barrier(0);
    quad2(6, AfB);
    __builtin_amdgcn_s_barrier();
  }

  // ---- epilogue: exp(sim-10), row/col partial sums (reuse tile LDS) ----
  float* red_row = (float*)Tile;           // [4][256] floats (by wn)
  float* red_col = (float*)Tile + 1024;    // [2][256] floats (by wm)

#pragma unroll
  for (int m = 0; m < 8; ++m)
#pragma unroll
    for (int n = 0; n < 4; ++n) {
      f32x4 v = acc[m][n];
#pragma unroll
      for (int r = 0; r < 4; ++r) v[r] = __builtin_amdgcn_exp2f((v[r] - 1.0f) * C_EXPSCALE);
      acc[m][n] = v;
    }

#pragma unroll
  for (int m = 0; m < 8; ++m)
#pragma unroll
    for (int r = 0; r < 4; ++r) {
      float s = acc[m][0][r] + acc[m][1][r] + acc[m][2][r] + acc[m][3][r];
      s += __shfl_xor(s, 1, 64);
      s += __shfl_xor(s, 2, 64);
      s += __shfl_xor(s, 4, 64);
      s += __shfl_xor(s, 8, 64);
      if (l15 == 0) red_row[wn * 256 + wm * 128 + m * 16 + lhi * 4 + r] = s;
    }
#pragma unroll
  for (int n = 0; n < 4; ++n) {
    float s = 0.f;
#pragma unroll
    for (int m = 0; m < 8; ++m)
      s += acc[m][n][0] + acc[m][n][1] + acc[m][n][2] + acc[m][n][3];
    s += __shfl_xor(s, 16, 64);
    s += __shfl_xor(s, 32, 64);
    if (lane < 16) red_col[wm * 256 + wn * 64 + n * 16 + lane] = s;
  }
  __syncthreads();

  if (tid < 256) {
    float s = red_row[tid] + red_row[256 + tid] + red_row[512 + tid] + red_row[768 + tid];
    atomicAdd(&row_sum[br + tid], s);
  } else {
    const int c = tid - 256;
    float s = red_col[c] + red_col[256 + c];
    atomicAdd(&col_sum[bc + c], s);
  }
}

// ---------------- finalize ----------------
__global__ __launch_bounds__(1024) void finalize_kernel(const float* __restrict__ row_sum,
                                                        const float* __restrict__ col_sum,
                                                        const float* __restrict__ diag,
                                                        float* __restrict__ out) {
  __shared__ float sred[1024];
  float acc = 0.0f;
  for (int i = threadIdx.x; i < N_ROWS; i += 1024) {
    const float lse_r = 10.0f + logf(row_sum[i]);
    const float lse_c = 10.0f + logf(col_sum[i]);
    acc += 0.75f * lse_r + 0.25f * lse_c - diag[i];
  }
  sred[threadIdx.x] = acc;
  __syncthreads();
  for (int s = 512; s > 0; s >>= 1) {
    if ((int)threadIdx.x < s) sred[threadIdx.x] += sred[threadIdx.x + s];
    __syncthreads();
  }
  if (threadIdx.x == 0) out[0] = sred[0] / (float)N_ROWS;
}

extern "C" void kernel_launch(void* const* d_in, const int* in_sizes, int n_in,
                              void* d_out, int out_size, void* d_ws, size_t ws_size,
                              hipStream_t stream) {
  const float* V = (const float*)d_in[0];
  const float* U = (const float*)d_in[1];
  float* out = (float*)d_out;

  char* ws = (char*)d_ws;
  ushort* Vn      = (ushort*)(ws);
  ushort* Un      = (ushort*)(ws + 8388608);
  float*  diag    = (float*)(ws + 16777216);
  float*  row_sum = (float*)(ws + 16777216 + 32768);
  float*  col_sum = (float*)(ws + 16777216 + 65536);

  prep_kernel<<<N_ROWS / 4, 256, 0, stream>>>(V, U, Vn, Un, diag, row_sum, col_sum);
  gemm_lse_kernel<<<(N_ROWS / 256) * (N_ROWS / 256), 512, 0, stream>>>(Vn, Un, row_sum, col_sum);
  finalize_kernel<<<1, 1024, 0, stream>>>(row_sum, col_sum, diag, out);
}